// Round 1
// baseline (283.890 us; speedup 1.0000x reference)
//
#include <hip/hip_runtime.h>

#define B_  8
#define T_  16
#define N_  1024
#define FI  32
#define FO  64
#define K_  3

typedef float  f32x4  __attribute__((ext_vector_type(4)));
typedef short  bf16x8 __attribute__((ext_vector_type(8)));
typedef unsigned short u16x8 __attribute__((ext_vector_type(8)));

__device__ inline unsigned short f2bf(float f) {
    // round-to-nearest-even fp32 -> bf16 (inputs are finite)
    unsigned int u = __float_as_uint(f);
    u += 0x7fffu + ((u >> 16) & 1u);
    return (unsigned short)(u >> 16);
}

// ---------------------------------------------------------------------------
// Kernel 1: x[b,t,j,f] (fp32) -> xt[b, t*32+f, j] (bf16)   [B][512][1024]
// grid: B_*T_*(N_/64) = 2048 blocks, 256 threads
// ---------------------------------------------------------------------------
__global__ __launch_bounds__(256)
void transpose_x(const float* __restrict__ x, unsigned short* __restrict__ xt) {
    int blk = blockIdx.x;
    int jt  = blk & 15;           // N_/64 = 16 tiles of j
    int bt  = blk >> 4;           // b*T_+t, 0..127
    int j0  = jt * 64;
    const float* src = x + (size_t)bt * (N_ * FI) + (size_t)j0 * FI;

    __shared__ __align__(16) float tile[64][33];
    int tid = threadIdx.x;

    #pragma unroll
    for (int s = 0; s < 2; s++) {
        int e4 = tid + s * 256;          // 0..511 float4s of the 64x32 tile
        int j  = e4 >> 3;                // 8 float4 per j-row
        int f4 = e4 & 7;
        f32x4 v = *(const f32x4*)(src + j * FI + f4 * 4);
        tile[j][f4 * 4 + 0] = v[0];
        tile[j][f4 * 4 + 1] = v[1];
        tile[j][f4 * 4 + 2] = v[2];
        tile[j][f4 * 4 + 3] = v[3];
    }
    __syncthreads();

    // xt offset: b*512*1024 + (t*32+f)*1024 + j0 + j  ==  bt*32768 + f*1024 + j0 + j
    unsigned short* dst = xt + (size_t)bt * (32 * 1024) + j0;
    #pragma unroll
    for (int s = 0; s < 8; s++) {
        int e = tid + s * 256;           // 0..2047
        int f = e >> 6;
        int j = e & 63;
        dst[f * 1024 + j] = f2bf(tile[j][f]);
    }
}

// ---------------------------------------------------------------------------
// Kernel 2: rhs[b,t,i, k*32+f] = sum_j (cheb[k,i,j]*att[b,i,j]) * x[b,t,j,f]
// One GEMM per (b,k): C[i, c] = A[i,:] . Xt[c,:],  M=1024, Ncol=512, Kd=1024
// A is fused cheb*att -> bf16 during LDS staging.
// grid: (4 colTiles, 8 rowTiles, 24 b*k), 256 threads (4 waves, 64x64 each)
// ---------------------------------------------------------------------------
__global__ __launch_bounds__(256)
void stage1_gemm(const float* __restrict__ cheb, const float* __restrict__ att,
                 const unsigned short* __restrict__ xt, float* __restrict__ rhs) {
    int bk = blockIdx.z;
    int b  = bk / K_;
    int kk = bk - b * K_;
    int i0 = blockIdx.y * 128;
    int c0 = blockIdx.x * 128;

    const float* chebK = cheb + (size_t)kk * N_ * N_;
    const float* attB  = att  + (size_t)b  * N_ * N_;
    const unsigned short* xtB = xt + (size_t)b * (512 * 1024);

    __shared__ __align__(16) unsigned short As[128 * 32];
    __shared__ __align__(16) unsigned short Bs[128 * 32];

    int tid  = threadIdx.x;
    int lane = tid & 63;
    int w    = tid >> 6;
    int wrow = (w >> 1) * 64;
    int wcol = (w & 1) * 64;
    int quad = lane >> 4;
    int l15  = lane & 15;

    f32x4 acc[4][4];
    #pragma unroll
    for (int mt = 0; mt < 4; mt++)
        #pragma unroll
        for (int nt = 0; nt < 4; nt++)
            acc[mt][nt] = (f32x4){0.f, 0.f, 0.f, 0.f};

    int r    = tid >> 1;          // 0..127 staging row
    int half = (tid & 1) * 16;    // 16-element half of the 32-wide k chunk

    for (int kb = 0; kb < 32; kb++) {
        int j0 = kb * 32;
        __syncthreads();
        // ---- stage A: fused cheb*att -> bf16 ----
        {
            const float* cp = chebK + (size_t)(i0 + r) * N_ + j0 + half;
            const float* ap = attB  + (size_t)(i0 + r) * N_ + j0 + half;
            f32x4 cv0 = ((const f32x4*)cp)[0];
            f32x4 cv1 = ((const f32x4*)cp)[1];
            f32x4 cv2 = ((const f32x4*)cp)[2];
            f32x4 cv3 = ((const f32x4*)cp)[3];
            f32x4 av0 = ((const f32x4*)ap)[0];
            f32x4 av1 = ((const f32x4*)ap)[1];
            f32x4 av2 = ((const f32x4*)ap)[2];
            f32x4 av3 = ((const f32x4*)ap)[3];
            u16x8 p0, p1;
            #pragma unroll
            for (int u = 0; u < 4; u++) {
                p0[u]     = f2bf(cv0[u] * av0[u]);
                p0[u + 4] = f2bf(cv1[u] * av1[u]);
                p1[u]     = f2bf(cv2[u] * av2[u]);
                p1[u + 4] = f2bf(cv3[u] * av3[u]);
            }
            *(u16x8*)(As + r * 32 + half)     = p0;
            *(u16x8*)(As + r * 32 + half + 8) = p1;
        }
        // ---- stage B: copy bf16 ----
        {
            const u16x8* bp = (const u16x8*)(xtB + (size_t)(c0 + r) * 1024 + j0 + half);
            *(u16x8*)(Bs + r * 32 + half)     = bp[0];
            *(u16x8*)(Bs + r * 32 + half + 8) = bp[1];
        }
        __syncthreads();
        // ---- MFMA ----
        bf16x8 af[4], bfr[4];
        #pragma unroll
        for (int mt = 0; mt < 4; mt++)
            af[mt] = *(const bf16x8*)(As + (wrow + mt * 16 + l15) * 32 + quad * 8);
        #pragma unroll
        for (int nt = 0; nt < 4; nt++)
            bfr[nt] = *(const bf16x8*)(Bs + (wcol + nt * 16 + l15) * 32 + quad * 8);
        #pragma unroll
        for (int mt = 0; mt < 4; mt++)
            #pragma unroll
            for (int nt = 0; nt < 4; nt++)
                acc[mt][nt] = __builtin_amdgcn_mfma_f32_16x16x32_bf16(
                    af[mt], bfr[nt], acc[mt][nt], 0, 0, 0);
    }

    // ---- epilogue: C/D layout col=lane&15 (c), row=quad*4+reg (i) ----
    #pragma unroll
    for (int mt = 0; mt < 4; mt++) {
        #pragma unroll
        for (int nt = 0; nt < 4; nt++) {
            int ci = c0 + wcol + nt * 16 + l15;   // 0..511  (= t*32+f)
            int tt = ci >> 5;
            int ff = ci & 31;
            #pragma unroll
            for (int reg = 0; reg < 4; reg++) {
                int ii = i0 + wrow + mt * 16 + quad * 4 + reg;
                rhs[(((size_t)b * T_ + tt) * N_ + ii) * 96 + kk * 32 + ff] =
                    acc[mt][nt][reg];
            }
        }
    }
}

// ---------------------------------------------------------------------------
// Kernel 3: out[row, o] = relu( sum_q rhs[row, q] * Theta[q, o] ), q = k*32+f
// Theta column held in 96 VGPRs per lane (lane = o); rhs row via broadcast
// loads. grid: 1024 blocks x 256 threads; each wave does 32 rows.
// ---------------------------------------------------------------------------
__global__ __launch_bounds__(256)
void stage2_proj(const float* __restrict__ rhs, const float* __restrict__ theta,
                 float* __restrict__ out) {
    int tid  = threadIdx.x;
    int lane = tid & 63;
    int gw   = blockIdx.x * 4 + (tid >> 6);   // 0..4095

    float th[96];
    #pragma unroll
    for (int q = 0; q < 96; q++) th[q] = theta[q * 64 + lane];

    size_t row0 = (size_t)gw * 32;
    for (int rr = 0; rr < 32; rr++) {
        size_t row = row0 + rr;
        const f32x4* rp = (const f32x4*)(rhs + row * 96);
        float acc = 0.f;
        #pragma unroll
        for (int q4 = 0; q4 < 24; q4++) {
            f32x4 v = rp[q4];
            acc += v[0] * th[q4 * 4 + 0];
            acc += v[1] * th[q4 * 4 + 1];
            acc += v[2] * th[q4 * 4 + 2];
            acc += v[3] * th[q4 * 4 + 3];
        }
        out[row * 64 + lane] = fmaxf(acc, 0.f);
    }
}

// ---------------------------------------------------------------------------
extern "C" void kernel_launch(void* const* d_in, const int* in_sizes, int n_in,
                              void* d_out, int out_size, void* d_ws, size_t ws_size,
                              hipStream_t stream) {
    const float* x     = (const float*)d_in[0];   // [B,T,N,FI]
    const float* att   = (const float*)d_in[1];   // [B,N,N]
    const float* cheb  = (const float*)d_in[2];   // [K,N,N]
    const float* theta = (const float*)d_in[3];   // [K,FI,FO]
    float* out = (float*)d_out;                   // [B,T,N,FO]

    // workspace layout: xt (bf16, 8 MB) | rhs (fp32, 50.3 MB)
    unsigned short* xt = (unsigned short*)d_ws;
    float* rhs = (float*)((char*)d_ws + (size_t)B_ * 512 * 1024 * sizeof(unsigned short));

    transpose_x<<<B_ * T_ * (N_ / 64), 256, 0, stream>>>(x, xt);
    stage1_gemm<<<dim3(512 / 128, N_ / 128, B_ * K_), 256, 0, stream>>>(cheb, att, xt, rhs);
    stage2_proj<<<(B_ * T_ * N_) / (4 * 32), 256, 0, stream>>>(rhs, theta, out);
}

// Round 2
// 193.566 us; speedup vs baseline: 1.4666x; 1.4666x over previous
//
#include <hip/hip_runtime.h>
#include <hip/hip_bf16.h>

#define B_  8
#define T_  16
#define N_  1024
#define FI  32
#define FO  64
#define K_  3

// padded LDS row stride (shorts) for stage1 tiles: 40*2B = 80 B = 20 words,
// l15*20 % 32 cycles through 8 banks -> 2-way aliasing (free on gfx950)
#define LDA 40

typedef float  f32x4  __attribute__((ext_vector_type(4)));
typedef short  bf16x8 __attribute__((ext_vector_type(8)));
typedef unsigned short u16x8 __attribute__((ext_vector_type(8)));
typedef unsigned int   u32x4 __attribute__((ext_vector_type(4)));

__device__ inline unsigned short f2bf(float f) {
    unsigned int u = __float_as_uint(f);
    u += 0x7fffu + ((u >> 16) & 1u);
    return (unsigned short)(u >> 16);
}

// packed fp32x2 -> bf16x2 (v_cvt_pk_bf16_f32 on gfx950)
__device__ inline unsigned int pkbf2(float a, float b) {
    __hip_bfloat162 h = __float22bfloat162_rn(make_float2(a, b));
    union { __hip_bfloat162 h2; unsigned int u; } cvt;
    cvt.h2 = h;
    return cvt.u;
}

// ---------------------------------------------------------------------------
// Kernel 1: x[b,t,j,f] (fp32) -> xt[b, t*32+f, j] (bf16)   [B][512][1024]
// grid: B_*T_*(N_/64) = 2048 blocks, 256 threads
// ---------------------------------------------------------------------------
__global__ __launch_bounds__(256)
void transpose_x(const float* __restrict__ x, unsigned short* __restrict__ xt) {
    int blk = blockIdx.x;
    int jt  = blk & 15;           // N_/64 = 16 tiles of j
    int bt  = blk >> 4;           // b*T_+t, 0..127
    int j0  = jt * 64;
    const float* src = x + (size_t)bt * (N_ * FI) + (size_t)j0 * FI;

    __shared__ __align__(16) float tile[64][33];
    int tid = threadIdx.x;

    #pragma unroll
    for (int s = 0; s < 2; s++) {
        int e4 = tid + s * 256;          // 0..511 float4s of the 64x32 tile
        int j  = e4 >> 3;                // 8 float4 per j-row
        int f4 = e4 & 7;
        f32x4 v = *(const f32x4*)(src + j * FI + f4 * 4);
        tile[j][f4 * 4 + 0] = v[0];
        tile[j][f4 * 4 + 1] = v[1];
        tile[j][f4 * 4 + 2] = v[2];
        tile[j][f4 * 4 + 3] = v[3];
    }
    __syncthreads();

    // each thread packs 8 consecutive j for one f -> one 16-B store
    int f  = tid >> 3;            // 0..31
    int j8 = (tid & 7) * 8;       // 0..56
    u32x4 pk;
    #pragma unroll
    for (int u = 0; u < 4; u++)
        pk[u] = pkbf2(tile[j8 + 2 * u][f], tile[j8 + 2 * u + 1][f]);
    unsigned short* dst = xt + (size_t)bt * (32 * 1024) + j0;
    *(u32x4*)(dst + f * 1024 + j8) = pk;
}

// ---------------------------------------------------------------------------
// Kernel 2: rhs_bf16[b,t,i, k*32+f] = sum_j (cheb[k,i,j]*att[b,i,j]) * x[b,t,j,f]
// One GEMM per (b,k): C[i, c] = A[i,:] . Xt[c,:],  M=1024, Ncol=512, Kd=1024
// grid: (4 colTiles, 8 rowTiles, 24 b*k), 256 threads (4 waves, 64x64 each)
// ---------------------------------------------------------------------------
__global__ __launch_bounds__(256)
void stage1_gemm(const float* __restrict__ cheb, const float* __restrict__ att,
                 const unsigned short* __restrict__ xt,
                 unsigned short* __restrict__ rhs) {
    int bk = blockIdx.z;
    int b  = bk / K_;
    int kk = bk - b * K_;
    int i0 = blockIdx.y * 128;
    int c0 = blockIdx.x * 128;

    const float* chebK = cheb + (size_t)kk * N_ * N_;
    const float* attB  = att  + (size_t)b  * N_ * N_;
    const unsigned short* xtB = xt + (size_t)b * (512 * 1024);

    __shared__ __align__(16) unsigned short As[128 * LDA];
    __shared__ __align__(16) unsigned short Bs[128 * LDA];

    int tid  = threadIdx.x;
    int lane = tid & 63;
    int w    = tid >> 6;
    int wrow = (w >> 1) * 64;
    int wcol = (w & 1) * 64;
    int quad = lane >> 4;
    int l15  = lane & 15;

    f32x4 acc[4][4];
    #pragma unroll
    for (int mt = 0; mt < 4; mt++)
        #pragma unroll
        for (int nt = 0; nt < 4; nt++)
            acc[mt][nt] = (f32x4){0.f, 0.f, 0.f, 0.f};

    int r    = tid >> 1;          // 0..127 staging row
    int half = (tid & 1) * 16;    // 16-element half of the 32-wide k chunk

    for (int kb = 0; kb < 32; kb++) {
        int j0 = kb * 32;
        __syncthreads();
        // ---- stage A: fused cheb*att -> bf16 (packed cvt) ----
        {
            const float* cp = chebK + (size_t)(i0 + r) * N_ + j0 + half;
            const float* ap = attB  + (size_t)(i0 + r) * N_ + j0 + half;
            f32x4 cv0 = ((const f32x4*)cp)[0];
            f32x4 cv1 = ((const f32x4*)cp)[1];
            f32x4 cv2 = ((const f32x4*)cp)[2];
            f32x4 cv3 = ((const f32x4*)cp)[3];
            f32x4 av0 = ((const f32x4*)ap)[0];
            f32x4 av1 = ((const f32x4*)ap)[1];
            f32x4 av2 = ((const f32x4*)ap)[2];
            f32x4 av3 = ((const f32x4*)ap)[3];
            u32x4 lo, hi;
            lo[0] = pkbf2(cv0[0] * av0[0], cv0[1] * av0[1]);
            lo[1] = pkbf2(cv0[2] * av0[2], cv0[3] * av0[3]);
            lo[2] = pkbf2(cv1[0] * av1[0], cv1[1] * av1[1]);
            lo[3] = pkbf2(cv1[2] * av1[2], cv1[3] * av1[3]);
            hi[0] = pkbf2(cv2[0] * av2[0], cv2[1] * av2[1]);
            hi[1] = pkbf2(cv2[2] * av2[2], cv2[3] * av2[3]);
            hi[2] = pkbf2(cv3[0] * av3[0], cv3[1] * av3[1]);
            hi[3] = pkbf2(cv3[2] * av3[2], cv3[3] * av3[3]);
            *(u32x4*)(As + r * LDA + half)     = lo;
            *(u32x4*)(As + r * LDA + half + 8) = hi;
        }
        // ---- stage B: copy bf16 ----
        {
            const u16x8* bp = (const u16x8*)(xtB + (size_t)(c0 + r) * 1024 + j0 + half);
            *(u16x8*)(Bs + r * LDA + half)     = bp[0];
            *(u16x8*)(Bs + r * LDA + half + 8) = bp[1];
        }
        __syncthreads();
        // ---- MFMA ----
        bf16x8 af[4], bfr[4];
        #pragma unroll
        for (int mt = 0; mt < 4; mt++)
            af[mt] = *(const bf16x8*)(As + (wrow + mt * 16 + l15) * LDA + quad * 8);
        #pragma unroll
        for (int nt = 0; nt < 4; nt++)
            bfr[nt] = *(const bf16x8*)(Bs + (wcol + nt * 16 + l15) * LDA + quad * 8);
        #pragma unroll
        for (int mt = 0; mt < 4; mt++)
            #pragma unroll
            for (int nt = 0; nt < 4; nt++)
                acc[mt][nt] = __builtin_amdgcn_mfma_f32_16x16x32_bf16(
                    af[mt], bfr[nt], acc[mt][nt], 0, 0, 0);
    }

    // ---- epilogue: C/D layout col=lane&15 (c), row=quad*4+reg (i); bf16 out ----
    #pragma unroll
    for (int mt = 0; mt < 4; mt++) {
        #pragma unroll
        for (int nt = 0; nt < 4; nt++) {
            int ci = c0 + wcol + nt * 16 + l15;   // 0..511  (= t*32+f)
            int tt = ci >> 5;
            int ff = ci & 31;
            #pragma unroll
            for (int reg = 0; reg < 4; reg++) {
                int ii = i0 + wrow + mt * 16 + quad * 4 + reg;
                rhs[(((size_t)b * T_ + tt) * N_ + ii) * 96 + kk * 32 + ff] =
                    f2bf(acc[mt][nt][reg]);
            }
        }
    }
}

// ---------------------------------------------------------------------------
// Kernel 3: out[row, o] = relu( sum_q rhs_bf16[row, q] * Theta[q, o] )
// MFMA GEMM: block tile = 128 rows x 64 o, q = 96 (3 chunks of 32).
// grid: 131072/128 = 1024 blocks, 256 threads (4 waves; wave w -> rows w*32..+31)
// ---------------------------------------------------------------------------
#define TS_LD 104   // Theta LDS row stride (shorts)
__global__ __launch_bounds__(256)
void stage2_mfma(const unsigned short* __restrict__ rhs,
                 const float* __restrict__ theta, float* __restrict__ out) {
    __shared__ __align__(16) unsigned short As[128 * 96];    // 24576 B, contiguous
    __shared__ __align__(16) unsigned short Ts[64 * TS_LD];  // Theta^T [o][q]

    int tid  = threadIdx.x;
    int lane = tid & 63;
    int w    = tid >> 6;
    int quad = lane >> 4;
    int l15  = lane & 15;
    size_t row0 = (size_t)blockIdx.x * 128;

    // stage Theta^T: theta[q*64+o] -> Ts[o*TS_LD+q] (bf16), 6144 elems
    #pragma unroll
    for (int s = 0; s < 24; s++) {
        int e = tid + s * 256;
        int q = e >> 6, o = e & 63;
        Ts[o * TS_LD + q] = f2bf(theta[e]);
    }
    // stage rhs tile: 128 rows x 96 q bf16 = 24576 B contiguous
    {
        const u16x8* g = (const u16x8*)(rhs + row0 * 96);
        u16x8* l = (u16x8*)As;
        #pragma unroll
        for (int s = 0; s < 6; s++)
            l[s * 256 + tid] = g[s * 256 + tid];
    }
    __syncthreads();

    f32x4 acc[2][4];
    #pragma unroll
    for (int mt = 0; mt < 2; mt++)
        #pragma unroll
        for (int nt = 0; nt < 4; nt++)
            acc[mt][nt] = (f32x4){0.f, 0.f, 0.f, 0.f};

    #pragma unroll
    for (int kc = 0; kc < 3; kc++) {
        bf16x8 bfr[4];
        #pragma unroll
        for (int nt = 0; nt < 4; nt++)
            bfr[nt] = *(const bf16x8*)(Ts + (nt * 16 + l15) * TS_LD + kc * 32 + quad * 8);
        #pragma unroll
        for (int mt = 0; mt < 2; mt++) {
            bf16x8 af = *(const bf16x8*)(As + (w * 32 + mt * 16 + l15) * 96 + kc * 32 + quad * 8);
            #pragma unroll
            for (int nt = 0; nt < 4; nt++)
                acc[mt][nt] = __builtin_amdgcn_mfma_f32_16x16x32_bf16(
                    af, bfr[nt], acc[mt][nt], 0, 0, 0);
        }
    }

    // epilogue: row = quad*4+reg, col(o) = l15
    #pragma unroll
    for (int mt = 0; mt < 2; mt++) {
        #pragma unroll
        for (int nt = 0; nt < 4; nt++) {
            int o = nt * 16 + l15;
            #pragma unroll
            for (int reg = 0; reg < 4; reg++) {
                size_t row = row0 + w * 32 + mt * 16 + quad * 4 + reg;
                out[row * 64 + o] = fmaxf(acc[mt][nt][reg], 0.f);
            }
        }
    }
}

// ---------------------------------------------------------------------------
extern "C" void kernel_launch(void* const* d_in, const int* in_sizes, int n_in,
                              void* d_out, int out_size, void* d_ws, size_t ws_size,
                              hipStream_t stream) {
    const float* x     = (const float*)d_in[0];   // [B,T,N,FI]
    const float* att   = (const float*)d_in[1];   // [B,N,N]
    const float* cheb  = (const float*)d_in[2];   // [K,N,N]
    const float* theta = (const float*)d_in[3];   // [K,FI,FO]
    float* out = (float*)d_out;                   // [B,T,N,FO]

    // workspace layout: xt (bf16, 8.4 MB) | rhs (bf16, 25.2 MB)
    unsigned short* xt  = (unsigned short*)d_ws;
    unsigned short* rhs = (unsigned short*)((char*)d_ws +
                          (size_t)B_ * 512 * 1024 * sizeof(unsigned short));

    transpose_x<<<B_ * T_ * (N_ / 64), 256, 0, stream>>>(x, xt);
    stage1_gemm<<<dim3(512 / 128, N_ / 128, B_ * K_), 256, 0, stream>>>(cheb, att, xt, rhs);
    stage2_mfma<<<(B_ * T_ * N_) / 128, 256, 0, stream>>>(rhs, theta, out);
}

// Round 3
// 160.258 us; speedup vs baseline: 1.7715x; 1.2078x over previous
//
#include <hip/hip_runtime.h>
#include <hip/hip_bf16.h>

#define B_  8
#define T_  16
#define N_  1024
#define FI  32
#define FO  64
#define K_  3

typedef float  f32x4  __attribute__((ext_vector_type(4)));
typedef short  bf16x8 __attribute__((ext_vector_type(8)));
typedef unsigned short u16x8 __attribute__((ext_vector_type(8)));
typedef unsigned int   u32x4 __attribute__((ext_vector_type(4)));

__device__ inline unsigned short f2bf(float f) {
    unsigned int u = __float_as_uint(f);
    u += 0x7fffu + ((u >> 16) & 1u);
    return (unsigned short)(u >> 16);
}

// packed fp32x2 -> bf16x2 (v_cvt_pk_bf16_f32 on gfx950)
__device__ inline unsigned int pkbf2(float a, float b) {
    __hip_bfloat162 h = __float22bfloat162_rn(make_float2(a, b));
    union { __hip_bfloat162 h2; unsigned int u; } cvt;
    cvt.h2 = h;
    return cvt.u;
}

// async 16-B global -> LDS (global_load_lds_dwordx4). LDS dest must be
// wave-uniform-base + lane*16 -- our tid*16B contiguous mapping satisfies it.
__device__ inline void gl_lds16(const unsigned short* g, unsigned short* l) {
    __builtin_amdgcn_global_load_lds(
        (const __attribute__((address_space(1))) unsigned int*)g,
        (__attribute__((address_space(3))) unsigned int*)l, 16, 0, 0);
}

// ---------------------------------------------------------------------------
// Kernel 0: AC[b,k,i,j] = cheb[k,i,j] * att[b,i,j]  (bf16)
// one thread: 8 j-elems for one (b,ij), loops k (att read once).
// grid: B_*N_*N_/8/256 = 4096 blocks
// ---------------------------------------------------------------------------
__global__ __launch_bounds__(256)
void fuse_ac(const float* __restrict__ cheb, const float* __restrict__ att,
             unsigned short* __restrict__ ac) {
    int e  = blockIdx.x * 256 + threadIdx.x;   // 0..1048575
    int b  = e >> 17;
    int ij = (e & 131071) * 8;
    const float* ap = att + (size_t)b * (N_ * N_) + ij;
    f32x4 a0 = ((const f32x4*)ap)[0];
    f32x4 a1 = ((const f32x4*)ap)[1];
    #pragma unroll
    for (int k = 0; k < K_; k++) {
        const float* cp = cheb + (size_t)k * (N_ * N_) + ij;
        f32x4 c0 = ((const f32x4*)cp)[0];
        f32x4 c1 = ((const f32x4*)cp)[1];
        u32x4 pk;
        pk[0] = pkbf2(c0[0] * a0[0], c0[1] * a0[1]);
        pk[1] = pkbf2(c0[2] * a0[2], c0[3] * a0[3]);
        pk[2] = pkbf2(c1[0] * a1[0], c1[1] * a1[1]);
        pk[3] = pkbf2(c1[2] * a1[2], c1[3] * a1[3]);
        *(u32x4*)(ac + (size_t)(b * K_ + k) * (N_ * N_) + ij) = pk;
    }
}

// ---------------------------------------------------------------------------
// Kernel 1: x[b,t,j,f] (fp32) -> xt[b, t*32+f, j] (bf16)   [B][512][1024]
// ---------------------------------------------------------------------------
__global__ __launch_bounds__(256)
void transpose_x(const float* __restrict__ x, unsigned short* __restrict__ xt) {
    int blk = blockIdx.x;
    int jt  = blk & 15;
    int bt  = blk >> 4;
    int j0  = jt * 64;
    const float* src = x + (size_t)bt * (N_ * FI) + (size_t)j0 * FI;

    __shared__ __align__(16) float tile[64][33];
    int tid = threadIdx.x;

    #pragma unroll
    for (int s = 0; s < 2; s++) {
        int e4 = tid + s * 256;
        int j  = e4 >> 3;
        int f4 = e4 & 7;
        f32x4 v = *(const f32x4*)(src + j * FI + f4 * 4);
        tile[j][f4 * 4 + 0] = v[0];
        tile[j][f4 * 4 + 1] = v[1];
        tile[j][f4 * 4 + 2] = v[2];
        tile[j][f4 * 4 + 3] = v[3];
    }
    __syncthreads();

    int f  = tid >> 3;
    int j8 = (tid & 7) * 8;
    u32x4 pk;
    #pragma unroll
    for (int u = 0; u < 4; u++)
        pk[u] = pkbf2(tile[j8 + 2 * u][f], tile[j8 + 2 * u + 1][f]);
    unsigned short* dst = xt + (size_t)bt * (32 * 1024) + j0;
    *(u32x4*)(dst + f * 1024 + j8) = pk;
}

// ---------------------------------------------------------------------------
// Kernel 2: rhs_bf16[b,t,i, k*32+f] = sum_j AC[b,k,i,j] * xt[b, t*32+f, j]
// pure bf16 GEMM (m97 structure): 128x128 tile, BK=32, global_load_lds x16.
// grid: (4 colTiles, 8 rowTiles, 24 b*k), 256 threads (4 waves, 64x64)
// ---------------------------------------------------------------------------
__global__ __launch_bounds__(256)
void stage1_gemm(const unsigned short* __restrict__ ac,
                 const unsigned short* __restrict__ xt,
                 unsigned short* __restrict__ rhs) {
    int bk = blockIdx.z;
    int b  = bk / K_;
    int kk = bk - b * K_;
    int i0 = blockIdx.y * 128;
    int c0 = blockIdx.x * 128;

    const unsigned short* A  = ac + (size_t)bk * (N_ * N_);
    const unsigned short* Bx = xt + (size_t)b * (512 * 1024);

    __shared__ __align__(16) unsigned short As[128 * 32];  // unpadded: lds-DMA
    __shared__ __align__(16) unsigned short Bs[128 * 32];

    int tid  = threadIdx.x;
    int lane = tid & 63;
    int w    = tid >> 6;
    int wrow = (w >> 1) * 64;
    int wcol = (w & 1) * 64;
    int quad = lane >> 4;
    int l15  = lane & 15;

    f32x4 acc[4][4];
    #pragma unroll
    for (int mt = 0; mt < 4; mt++)
        #pragma unroll
        for (int nt = 0; nt < 4; nt++)
            acc[mt][nt] = (f32x4){0.f, 0.f, 0.f, 0.f};

    int sr = tid >> 2;          // staging row 0..63 (and +64)
    int sc = (tid & 3) * 8;     // k-elem offset 0/8/16/24

    const unsigned short* Ag = A  + (size_t)(i0 + sr) * N_ + sc;
    const unsigned short* Bg = Bx + (size_t)(c0 + sr) * N_ + sc;
    unsigned short* Al = As + tid * 8;
    unsigned short* Bl = Bs + tid * 8;

    for (int kb = 0; kb < 32; kb++) {
        int j0 = kb * 32;
        __syncthreads();
        gl_lds16(Ag + j0,            Al);
        gl_lds16(Ag + j0 + 64 * N_,  Al + 64 * 32);
        gl_lds16(Bg + j0,            Bl);
        gl_lds16(Bg + j0 + 64 * N_,  Bl + 64 * 32);
        __syncthreads();   // compiler emits s_waitcnt vmcnt(0) before barrier

        bf16x8 af[4], bfr[4];
        #pragma unroll
        for (int mt = 0; mt < 4; mt++)
            af[mt] = *(const bf16x8*)(As + (wrow + mt * 16 + l15) * 32 + quad * 8);
        #pragma unroll
        for (int nt = 0; nt < 4; nt++)
            bfr[nt] = *(const bf16x8*)(Bs + (wcol + nt * 16 + l15) * 32 + quad * 8);
        #pragma unroll
        for (int mt = 0; mt < 4; mt++)
            #pragma unroll
            for (int nt = 0; nt < 4; nt++)
                acc[mt][nt] = __builtin_amdgcn_mfma_f32_16x16x32_bf16(
                    af[mt], bfr[nt], acc[mt][nt], 0, 0, 0);
    }

    // epilogue: C/D layout col=lane&15 (c), row=quad*4+reg (i); bf16 out
    #pragma unroll
    for (int mt = 0; mt < 4; mt++) {
        #pragma unroll
        for (int nt = 0; nt < 4; nt++) {
            int ci = c0 + wcol + nt * 16 + l15;   // = t*32+f
            int tt = ci >> 5;
            int ff = ci & 31;
            #pragma unroll
            for (int reg = 0; reg < 4; reg++) {
                int ii = i0 + wrow + mt * 16 + quad * 4 + reg;
                rhs[(((size_t)b * T_ + tt) * N_ + ii) * 96 + kk * 32 + ff] =
                    f2bf(acc[mt][nt][reg]);
            }
        }
    }
}

// ---------------------------------------------------------------------------
// Kernel 3: out[row, o] = relu( sum_q rhs_bf16[row, q] * Theta[q, o] )
// ---------------------------------------------------------------------------
#define TS_LD 104
__global__ __launch_bounds__(256)
void stage2_mfma(const unsigned short* __restrict__ rhs,
                 const float* __restrict__ theta, float* __restrict__ out) {
    __shared__ __align__(16) unsigned short As[128 * 96];
    __shared__ __align__(16) unsigned short Ts[64 * TS_LD];

    int tid  = threadIdx.x;
    int lane = tid & 63;
    int w    = tid >> 6;
    int quad = lane >> 4;
    int l15  = lane & 15;
    size_t row0 = (size_t)blockIdx.x * 128;

    #pragma unroll
    for (int s = 0; s < 24; s++) {
        int e = tid + s * 256;
        int q = e >> 6, o = e & 63;
        Ts[o * TS_LD + q] = f2bf(theta[e]);
    }
    {
        const u16x8* g = (const u16x8*)(rhs + row0 * 96);
        u16x8* l = (u16x8*)As;
        #pragma unroll
        for (int s = 0; s < 6; s++)
            l[s * 256 + tid] = g[s * 256 + tid];
    }
    __syncthreads();

    f32x4 acc[2][4];
    #pragma unroll
    for (int mt = 0; mt < 2; mt++)
        #pragma unroll
        for (int nt = 0; nt < 4; nt++)
            acc[mt][nt] = (f32x4){0.f, 0.f, 0.f, 0.f};

    #pragma unroll
    for (int kc = 0; kc < 3; kc++) {
        bf16x8 bfr[4];
        #pragma unroll
        for (int nt = 0; nt < 4; nt++)
            bfr[nt] = *(const bf16x8*)(Ts + (nt * 16 + l15) * TS_LD + kc * 32 + quad * 8);
        #pragma unroll
        for (int mt = 0; mt < 2; mt++) {
            bf16x8 af = *(const bf16x8*)(As + (w * 32 + mt * 16 + l15) * 96 + kc * 32 + quad * 8);
            #pragma unroll
            for (int nt = 0; nt < 4; nt++)
                acc[mt][nt] = __builtin_amdgcn_mfma_f32_16x16x32_bf16(
                    af, bfr[nt], acc[mt][nt], 0, 0, 0);
        }
    }

    #pragma unroll
    for (int mt = 0; mt < 2; mt++) {
        #pragma unroll
        for (int nt = 0; nt < 4; nt++) {
            int o = nt * 16 + l15;
            #pragma unroll
            for (int reg = 0; reg < 4; reg++) {
                size_t row = row0 + w * 32 + mt * 16 + quad * 4 + reg;
                out[row * 64 + o] = fmaxf(acc[mt][nt][reg], 0.f);
            }
        }
    }
}

// ---------------------------------------------------------------------------
extern "C" void kernel_launch(void* const* d_in, const int* in_sizes, int n_in,
                              void* d_out, int out_size, void* d_ws, size_t ws_size,
                              hipStream_t stream) {
    const float* x     = (const float*)d_in[0];   // [B,T,N,FI]
    const float* att   = (const float*)d_in[1];   // [B,N,N]
    const float* cheb  = (const float*)d_in[2];   // [K,N,N]
    const float* theta = (const float*)d_in[3];   // [K,FI,FO]
    float* out = (float*)d_out;                   // [B,T,N,FO]

    // workspace: xt bf16 8.4 MB | rhs bf16 25.2 MB | ac bf16 50.3 MB = 84 MB
    unsigned short* xt  = (unsigned short*)d_ws;
    unsigned short* rhs = xt  + (size_t)B_ * 512 * 1024;
    unsigned short* ac  = rhs + (size_t)B_ * T_ * N_ * 96;

    fuse_ac<<<4096, 256, 0, stream>>>(cheb, att, ac);
    transpose_x<<<B_ * T_ * (N_ / 64), 256, 0, stream>>>(x, xt);
    stage1_gemm<<<dim3(512 / 128, N_ / 128, B_ * K_), 256, 0, stream>>>(ac, xt, rhs);
    stage2_mfma<<<(B_ * T_ * N_) / 128, 256, 0, stream>>>(rhs, theta, out);
}